// Round 8
// baseline (151.132 us; speedup 1.0000x reference)
//
#include <hip/hip_runtime.h>
#include <cstdint>

typedef __attribute__((ext_vector_type(8))) short short8;
typedef __attribute__((ext_vector_type(4))) float f32x4;
typedef unsigned int u32;
typedef unsigned short u16;

#define NTOK 2304
#define CDIM 384

__device__ __forceinline__ u16 f2bf(float f) {
    u32 u = __builtin_bit_cast(u32, f);
    u32 r = (u + 0x7FFFu + ((u >> 16) & 1u)) >> 16;
    return (u16)r;
}
__device__ __forceinline__ float bf2f(u32 h) {
    u32 u = h << 16;
    return __builtin_bit_cast(float, u);
}

// ---------------------------------------------------------------------------
// Merged transpose/cast.
// bz < 16 : x[bz] [384][2304] -> xT [2304][384] swz         (T only)
// bz == 16: w_qkv [384][1152] -> wqkvT [1152][384] swz; cols>=768 -> wv cast
// bz == 17: w_out [384][384]  -> woutT [384 j][384 cc] swz  (T only)
// swizzle: byte' = byte ^ ((row&7)<<4) on 16B chunks within each row.
// ---------------------------------------------------------------------------
__global__ __launch_bounds__(256) void transpose_all(
    const float* __restrict__ x, const float* __restrict__ w_qkv,
    const float* __restrict__ w_out,
    u16* __restrict__ xT, u16* __restrict__ wqkvT,
    u16* __restrict__ wv, u16* __restrict__ woutT)
{
    __shared__ float tile[64][65];
    const int bz = blockIdx.z;
    const float* src; int Csz; char* dT; char* dC = nullptr;
    int dcCol0 = 0; long dcRowB = 0; bool doC = false;
    if (bz < 16) {
        src = x + (long)bz * 384 * 2304; Csz = 2304;
        dT = (char*)(xT + (long)bz * 2304 * 384);
    } else if (bz == 16) {
        if (blockIdx.x >= 18) return;
        src = w_qkv; Csz = 1152;
        dT = (char*)wqkvT; dC = (char*)wv; dcCol0 = 768; dcRowB = 768; doC = true;
    } else {
        if (blockIdx.x >= 6) return;
        src = w_out; Csz = 384;
        dT = (char*)woutT;
    }
    const int c0 = blockIdx.x * 64;   // col-tile of src
    const int k0 = blockIdx.y * 64;   // row-tile of src
    const int t = threadIdx.x;
    const int rr = t >> 2, cc4 = (t & 3) * 16;

    const float* srow = src + (long)(k0 + rr) * Csz + c0 + cc4;
#pragma unroll
    for (int i = 0; i < 4; ++i) {
        float4 v = *(const float4*)(srow + i * 4);
        tile[rr][cc4 + i*4 + 0] = v.x;
        tile[rr][cc4 + i*4 + 1] = v.y;
        tile[rr][cc4 + i*4 + 2] = v.z;
        tile[rr][cc4 + i*4 + 3] = v.w;
    }
    __syncthreads();

    // transposed output: rows = c0+rr (src cols), row length 384
    {
        char* drow = dT + (long)(c0 + rr) * (CDIM * 2);
        const int sw = (rr & 7) << 4;
#pragma unroll
        for (int half = 0; half < 2; ++half) {
            u32 pk[4];
#pragma unroll
            for (int i = 0; i < 4; ++i) {
                float v0 = tile[cc4 + half*8 + 2*i][rr];
                float v1 = tile[cc4 + half*8 + 2*i + 1][rr];
                pk[i] = (u32)f2bf(v0) | ((u32)f2bf(v1) << 16);
            }
            uint4 q; q.x = pk[0]; q.y = pk[1]; q.z = pk[2]; q.w = pk[3];
            const int inrow = (k0 + cc4 + half*8) * 2;
            *(uint4*)(drow + (inrow ^ sw)) = q;
        }
    }
    // cast output (w_qkv v-cols only)
    if (doC && c0 >= dcCol0) {
        char* drow = dC + (long)(k0 + rr) * dcRowB;
        const int sw = (rr & 7) << 4;
#pragma unroll
        for (int half = 0; half < 2; ++half) {
            u32 pk[4];
#pragma unroll
            for (int i = 0; i < 4; ++i) {
                float v0 = tile[rr][cc4 + half*8 + 2*i];
                float v1 = tile[rr][cc4 + half*8 + 2*i + 1];
                pk[i] = (u32)f2bf(v0) | ((u32)f2bf(v1) << 16);
            }
            uint4 q; q.x = pk[0]; q.y = pk[1]; q.z = pk[2]; q.w = pk[3];
            const int inrow = (c0 - dcCol0 + cc4 + half*8) * 2;
            *(uint4*)(drow + (inrow ^ sw)) = q;
        }
    }
}

// ---------------------------------------------------------------------------
// G[b] = X X^T directly from f32 x. Reg-staged (issue-early loads, cvt->bf16,
// swizzled ds_write_b128) producing the exact LDS image the gload_lds path
// had; MFMA loop identical to mfma_gemm. 128x128 tile, BK=64, K=2304.
// Output: bf16 swz rows (MODE-2 layout). Grid (3,3,16).
// ---------------------------------------------------------------------------
__global__ __launch_bounds__(256) void g_gemm(
    const float* __restrict__ x, u16* __restrict__ Gs)
{
    __shared__ __attribute__((aligned(16))) u16 As[2][128 * 64];
    __shared__ __attribute__((aligned(16))) u16 Bs[2][128 * 64];
    const int lid = blockIdx.x + 3 * (blockIdx.y + 3 * blockIdx.z);
    const int swzid = (lid & 7) * 18 + (lid >> 3);   // NWG=144, bijective
    const int b = swzid / 9, rem = swzid % 9;
    const int m0 = (rem % 3) * 128, n0 = (rem / 3) * 128;
    const float* xb = x + (long)b * 384 * NTOK;

    const int t = threadIdx.x;
    const int w = t >> 6, l = t & 63;
    const int wm = (w >> 1) * 64, wn = (w & 1) * 64;
    const int rbase = t >> 3;            // 0..31
    const int col8 = (t & 7) * 8;        // token offset within k-slice
    const int wbyte = (t & 7) * 16;      // byte chunk within 128B row

    f32x4 acc[4][4] = {};
    float4 ra[8], rb[8];

    auto issue = [&](int kt) {
        const float* pa = xb + (long)(m0 + rbase) * NTOK + kt * 64 + col8;
        const float* pb = xb + (long)(n0 + rbase) * NTOK + kt * 64 + col8;
#pragma unroll
        for (int i = 0; i < 4; ++i) {
            ra[2*i]   = *(const float4*)(pa + (long)(32 * i) * NTOK);
            ra[2*i+1] = *(const float4*)(pa + (long)(32 * i) * NTOK + 4);
            rb[2*i]   = *(const float4*)(pb + (long)(32 * i) * NTOK);
            rb[2*i+1] = *(const float4*)(pb + (long)(32 * i) * NTOK + 4);
        }
    };
    auto cvtwrite = [&](int buf) {
#pragma unroll
        for (int i = 0; i < 4; ++i) {
            const int r = rbase + 32 * i;
            const int off = r * 128 + (wbyte ^ ((r & 7) << 4));
            uint4 qa, qb;
            qa.x = (u32)f2bf(ra[2*i].x)   | ((u32)f2bf(ra[2*i].y)   << 16);
            qa.y = (u32)f2bf(ra[2*i].z)   | ((u32)f2bf(ra[2*i].w)   << 16);
            qa.z = (u32)f2bf(ra[2*i+1].x) | ((u32)f2bf(ra[2*i+1].y) << 16);
            qa.w = (u32)f2bf(ra[2*i+1].z) | ((u32)f2bf(ra[2*i+1].w) << 16);
            qb.x = (u32)f2bf(rb[2*i].x)   | ((u32)f2bf(rb[2*i].y)   << 16);
            qb.y = (u32)f2bf(rb[2*i].z)   | ((u32)f2bf(rb[2*i].w)   << 16);
            qb.z = (u32)f2bf(rb[2*i+1].x) | ((u32)f2bf(rb[2*i+1].y) << 16);
            qb.w = (u32)f2bf(rb[2*i+1].z) | ((u32)f2bf(rb[2*i+1].w) << 16);
            *(uint4*)((char*)&As[buf][0] + off) = qa;
            *(uint4*)((char*)&Bs[buf][0] + off) = qb;
        }
    };

    issue(0);
    cvtwrite(0);
    __syncthreads();
    int cur = 0;
#pragma unroll 1
    for (int kt = 0; kt < 36; ++kt) {
        if (kt < 35) issue(kt + 1);
        const char* Ac = (const char*)&As[cur][0];
        const char* Bc = (const char*)&Bs[cur][0];
#pragma unroll
        for (int kk = 0; kk < 2; ++kk) {
            short8 af[4], bfr[4];
#pragma unroll
            for (int mi = 0; mi < 4; ++mi) {
                const int m = wm + mi * 16 + (l & 15);
                const int off = m * 128 + ((kk * 64 + (l >> 4) * 16) ^ ((m & 7) << 4));
                af[mi] = *(const short8*)(Ac + off);
            }
#pragma unroll
            for (int ni = 0; ni < 4; ++ni) {
                const int n = wn + ni * 16 + (l & 15);
                const int off = n * 128 + ((kk * 64 + (l >> 4) * 16) ^ ((n & 7) << 4));
                bfr[ni] = *(const short8*)(Bc + off);
            }
#pragma unroll
            for (int mi = 0; mi < 4; ++mi)
#pragma unroll
                for (int ni = 0; ni < 4; ++ni)
                    acc[mi][ni] = __builtin_amdgcn_mfma_f32_16x16x32_bf16(
                        af[mi], bfr[ni], acc[mi][ni], 0, 0, 0);
        }
        if (kt < 35) cvtwrite(cur ^ 1);
        __syncthreads();
        cur ^= 1;
    }

    // MODE-2 epilogue: bf16 swz rows
    char* Ob = (char*)Gs + (long)b * 294912;
#pragma unroll
    for (int mi = 0; mi < 4; ++mi) {
        const int mb = m0 + wm + mi * 16 + (l >> 4) * 4;
#pragma unroll
        for (int ni = 0; ni < 4; ++ni) {
            const int n = n0 + wn + ni * 16 + (l & 15);
#pragma unroll
            for (int r = 0; r < 4; ++r) {
                const int m = mb + r;
                const long byteoff = (long)m * 768 + (((long)n * 2) ^ ((m & 7) << 4));
                *(u16*)(Ob + byteoff) = f2bf(acc[mi][ni][r]);
            }
        }
    }
}

// ---------------------------------------------------------------------------
// Generalized MFMA GEMM (unchanged, proven): O[b][m][n] = sum_k A[m][k]*B[n][k]
// MODE 0: bf16 plain rows; MODE 1: f32 + bias; MODE 2: bf16 swz rows.
// ---------------------------------------------------------------------------
template<int MODE, int KT, int GX, int GY>
__global__ __launch_bounds__(256) void mfma_gemm(
    const u16* __restrict__ A, long aBatch,
    const u16* __restrict__ Bm, long bBatch,
    void* __restrict__ Ovoid, long oBatch, int ostride,
    const float* __restrict__ bias)
{
    constexpr int KB  = KT * 128;
    constexpr int KE  = KT * 64;
    constexpr int NWG = GX * GY * 16;
    __shared__ __attribute__((aligned(16))) u16 As[2][128 * 64];
    __shared__ __attribute__((aligned(16))) u16 Bs[2][128 * 64];

    const int lid = blockIdx.x + GX * (blockIdx.y + GY * blockIdx.z);
    const int swzid = (lid & 7) * (NWG / 8) + (lid >> 3);
    const int b   = swzid / (GX * GY);
    const int rem = swzid % (GX * GY);
    const int m0 = (rem % GX) * 128, n0 = (rem / GX) * 128;

    const u16* Ab = A + (long)b * aBatch + (long)m0 * KE;
    const u16* Bb = Bm + (long)b * bBatch + (long)n0 * KE;
    const int t = threadIdx.x;
    const int w = t >> 6, l = t & 63;
    const int wm = (w >> 1) * 64, wn = (w & 1) * 64;
    const int srow = t >> 3;
    const int scol = (t & 7) * 16;
    f32x4 acc[4][4] = {};

    auto stage = [&](int buf, int kt) {
        const int kbyte = kt * 128;
#pragma unroll
        for (int i = 0; i < 4; ++i) {
            const int row = srow + i * 32;
            const long so = (long)row * KB + kbyte + scol;
            const int d = (i * 256 + t) * 16;
            __builtin_amdgcn_global_load_lds(
                (const __attribute__((address_space(1))) u32*)((const char*)Ab + so),
                (__attribute__((address_space(3))) u32*)((char*)&As[buf][0] + d), 16, 0, 0);
            __builtin_amdgcn_global_load_lds(
                (const __attribute__((address_space(1))) u32*)((const char*)Bb + so),
                (__attribute__((address_space(3))) u32*)((char*)&Bs[buf][0] + d), 16, 0, 0);
        }
    };

    stage(0, 0);
    __syncthreads();
    int cur = 0;
#pragma unroll 1
    for (int kt = 0; kt < KT; ++kt) {
        if (kt < KT - 1) stage(cur ^ 1, kt + 1);
        const char* Ac = (const char*)&As[cur][0];
        const char* Bc = (const char*)&Bs[cur][0];
#pragma unroll
        for (int kk = 0; kk < 2; ++kk) {
            short8 af[4], bfr[4];
#pragma unroll
            for (int mi = 0; mi < 4; ++mi) {
                const int m = wm + mi * 16 + (l & 15);
                const int off = m * 128 + ((kk * 64 + (l >> 4) * 16) ^ ((m & 7) << 4));
                af[mi] = *(const short8*)(Ac + off);
            }
#pragma unroll
            for (int ni = 0; ni < 4; ++ni) {
                const int n = wn + ni * 16 + (l & 15);
                const int off = n * 128 + ((kk * 64 + (l >> 4) * 16) ^ ((n & 7) << 4));
                bfr[ni] = *(const short8*)(Bc + off);
            }
#pragma unroll
            for (int mi = 0; mi < 4; ++mi)
#pragma unroll
                for (int ni = 0; ni < 4; ++ni)
                    acc[mi][ni] = __builtin_amdgcn_mfma_f32_16x16x32_bf16(
                        af[mi], bfr[ni], acc[mi][ni], 0, 0, 0);
        }
        __syncthreads();
        cur ^= 1;
    }

    if (MODE == 0) {
        u16* O = (u16*)Ovoid + (long)b * oBatch;
#pragma unroll
        for (int mi = 0; mi < 4; ++mi) {
            const int mb = m0 + wm + mi * 16 + (l >> 4) * 4;
#pragma unroll
            for (int ni = 0; ni < 4; ++ni) {
                const int n = n0 + wn + ni * 16 + (l & 15);
#pragma unroll
                for (int r = 0; r < 4; ++r)
                    O[(long)(mb + r) * ostride + n] = f2bf(acc[mi][ni][r]);
            }
        }
    } else if (MODE == 1) {
        float* O = (float*)Ovoid + (long)b * oBatch;
#pragma unroll
        for (int mi = 0; mi < 4; ++mi) {
            const int mb = m0 + wm + mi * 16 + (l >> 4) * 4;
#pragma unroll
            for (int r = 0; r < 4; ++r) {
                const float bb = bias[mb + r];
#pragma unroll
                for (int ni = 0; ni < 4; ++ni) {
                    const int n = n0 + wn + ni * 16 + (l & 15);
                    O[(long)(mb + r) * ostride + n] = acc[mi][ni][r] + bb;
                }
            }
        }
    } else {
        char* Ob = (char*)Ovoid + (long)b * oBatch * 2;
#pragma unroll
        for (int mi = 0; mi < 4; ++mi) {
            const int mb = m0 + wm + mi * 16 + (l >> 4) * 4;
#pragma unroll
            for (int ni = 0; ni < 4; ++ni) {
                const int n = n0 + wn + ni * 16 + (l & 15);
#pragma unroll
                for (int r = 0; r < 4; ++r) {
                    const int m = mb + r;
                    const long byteoff = (long)m * (ostride * 2) +
                        (((long)n * 2) ^ ((m & 7) << 4));
                    *(u16*)(Ob + byteoff) = f2bf(acc[mi][ni][r]);
                }
            }
        }
    }
}

// ---------------------------------------------------------------------------
// Fused: S (MFMA, proven s_softmax phases) -> softmax -> S bf16 in LDS ->
// MFMA fold with woutT -> W2T bf16 swz. One block per (b,h), 256 thr.
// ---------------------------------------------------------------------------
__global__ __launch_bounds__(256) void sm_fold(
    const u16* __restrict__ Tp,     // [16][768][384] plain bf16
    const u16* __restrict__ wT,     // [1152][384] swz bf16
    const float* __restrict__ temp,
    const u16* __restrict__ woutT,  // [384 j][384 cc] swz bf16 (+slack)
    u16* __restrict__ W2T)          // [16][384][384] swz bf16
{
    __shared__ float Sp[4][48][48];
    __shared__ float S[48][49];
    __shared__ float invk[48], invq[48];
    __shared__ __attribute__((aligned(16))) u16 Sbf[48 * 64];
    const int h = blockIdx.x, b = blockIdx.y, t = threadIdx.x;
    const int w = t >> 6, l = t & 63, lr = l & 15, lk = (l >> 4) * 8;
    const int h48 = h * 48;

    // ---- S partials (proven) ----
    const u16* Tk = Tp + ((long)b * 768 + 384 + h48) * CDIM;
    {
        f32x4 acc[3][3] = {};
#pragma unroll
        for (int ks = 0; ks < 3; ++ks) {
            const int k0 = w * 96 + ks * 32 + lk;
            short8 af[3], bfr[3];
#pragma unroll
            for (int mi = 0; mi < 3; ++mi)
                af[mi] = *(const short8*)(Tk + (long)(mi * 16 + lr) * CDIM + k0);
#pragma unroll
            for (int ni = 0; ni < 3; ++ni) {
                const int row = h48 + ni * 16 + lr;
                const char* base = (const char*)wT + (long)row * 768;
                bfr[ni] = *(const short8*)(base + ((k0 * 2) ^ ((row & 7) << 4)));
            }
#pragma unroll
            for (int mi = 0; mi < 3; ++mi)
#pragma unroll
                for (int ni = 0; ni < 3; ++ni)
                    acc[mi][ni] = __builtin_amdgcn_mfma_f32_16x16x32_bf16(
                        af[mi], bfr[ni], acc[mi][ni], 0, 0, 0);
        }
#pragma unroll
        for (int mi = 0; mi < 3; ++mi)
#pragma unroll
            for (int ni = 0; ni < 3; ++ni)
#pragma unroll
                for (int r = 0; r < 4; ++r)
                    Sp[w][mi * 16 + (l >> 4) * 4 + r][ni * 16 + lr] = acc[mi][ni][r];
    }
    // ---- diag norms (proven) ----
    if (t < 96) {
        const int ch = (t < 48) ? (h48 + t) : (384 + h48 + (t - 48));
        const u16* trow = Tp + ((long)b * 768 + ch) * CDIM;
        const char* wrow = (const char*)wT + (long)ch * 768;
        const int sw = (ch & 7) << 4;
        float s = 0.f;
#pragma unroll 4
        for (int i = 0; i < 48; ++i) {
            short8 tv = *(const short8*)(trow + i * 8);
            short8 wv = *(const short8*)(wrow + ((i * 16) ^ sw));
#pragma unroll
            for (int e = 0; e < 8; ++e)
                s += bf2f((u16)tv[e]) * bf2f((u16)wv[e]);
        }
        float inv = 1.0f / fmaxf(sqrtf(fmaxf(s, 0.f)), 1e-12f);
        if (t < 48) invq[t] = inv; else invk[t - 48] = inv;
    }
    __syncthreads();
    for (int idx = t; idx < 2304; idx += 256) {
        const int p = idx / 48, q = idx % 48;
        S[p][q] = Sp[0][p][q] + Sp[1][p][q] + Sp[2][p][q] + Sp[3][p][q];
    }
    __syncthreads();
    // ---- softmax (proven) -> Sbf (bf16, 64-col zero-padded, swz) ----
    if (t < 48) {
        const float sc = temp[h] * invk[t];
        float row[48];
        float mx = -1e30f;
#pragma unroll 8
        for (int q = 0; q < 48; ++q) {
            row[q] = S[t][q] * sc * invq[q];
            mx = fmaxf(mx, row[q]);
        }
        float ssum = 0.f;
#pragma unroll 8
        for (int q = 0; q < 48; ++q) {
            row[q] = __expf(row[q] - mx);
            ssum += row[q];
        }
        float inv = 1.0f / ssum;
        const int sw = (t & 7) << 4;
#pragma unroll
        for (int g = 0; g < 8; ++g) {
            u32 pk[4];
#pragma unroll
            for (int e = 0; e < 4; ++e) {
                const int q0 = g * 8 + 2 * e;
                float v0 = (q0 < 48) ? row[q0] * inv : 0.f;
                float v1 = (q0 + 1 < 48) ? row[q0 + 1] * inv : 0.f;
                pk[e] = (u32)f2bf(v0) | ((u32)f2bf(v1) << 16);
            }
            uint4 qv; qv.x = pk[0]; qv.y = pk[1]; qv.z = pk[2]; qv.w = pk[3];
            *(uint4*)((char*)Sbf + t * 128 + ((g * 16) ^ sw)) = qv;
        }
    }
    __syncthreads();
    // ---- fold via MFMA: W2[p][j] = sum_q S[p][q] w_out[h48+q][j] ----
    // A = Sbf rows p (k=q, zero-padded to 64); B = woutT rows j (k=h48+q).
    {
        const char* SbfB = (const char*)Sbf;
        const int jw = w * 96;
        f32x4 fac[3][6] = {};
#pragma unroll
        for (int ks = 0; ks < 2; ++ks) {
            const int ka = ks * 64 + (l >> 4) * 16;   // byte k-offset (A)
            const int kb = h * 96 + ka;               // byte k-offset (B)
            short8 af[3], bfr[6];
#pragma unroll
            for (int mi = 0; mi < 3; ++mi) {
                const int p = mi * 16 + lr;
                af[mi] = *(const short8*)(SbfB + p * 128 + (ka ^ ((p & 7) << 4)));
            }
#pragma unroll
            for (int ni = 0; ni < 6; ++ni) {
                const int j = jw + ni * 16 + lr;
                bfr[ni] = *(const short8*)((const char*)woutT + (long)j * 768 +
                                           (kb ^ ((j & 7) << 4)));
            }
#pragma unroll
            for (int mi = 0; mi < 3; ++mi)
#pragma unroll
                for (int ni = 0; ni < 6; ++ni)
                    fac[mi][ni] = __builtin_amdgcn_mfma_f32_16x16x32_bf16(
                        af[mi], bfr[ni], fac[mi][ni], 0, 0, 0);
        }
        char* Wb = (char*)W2T + (long)b * 294912;
#pragma unroll
        for (int mi = 0; mi < 3; ++mi)
#pragma unroll
            for (int ni = 0; ni < 6; ++ni)
#pragma unroll
                for (int r = 0; r < 4; ++r) {
                    const int p = mi * 16 + (l >> 4) * 4 + r;
                    const int j = jw + ni * 16 + lr;
                    const long byteoff = (long)j * 768 +
                        (((h48 + p) * 2) ^ ((j & 7) << 4));
                    *(u16*)(Wb + byteoff) = f2bf(fac[mi][ni][r]);
                }
    }
}

// ---------------------------------------------------------------------------
extern "C" void kernel_launch(void* const* d_in, const int* in_sizes, int n_in,
                              void* d_out, int out_size, void* d_ws, size_t ws_size,
                              hipStream_t stream) {
    const float* x     = (const float*)d_in[0];  // [16][384][2304]
    const float* w_qkv = (const float*)d_in[1];  // [384][1152]
    const float* temp  = (const float*)d_in[2];  // [8]
    const float* w_out = (const float*)d_in[3];  // [384][384]
    const float* b_out = (const float*)d_in[4];  // [384]
    float* out = (float*)d_out;                  // [16][384][2304]

    char* ws = (char*)d_ws;
    const size_t SZ_XT  = 16UL * 2304 * 384 * 2;   // 28.3 MB
    const size_t SZ_WQT = 1152UL * 384 * 2;        // 0.88 MB
    const size_t SZ_WV  = 384UL * 384 * 2;         // 0.29 MB
    const size_t SZ_WOT = 384UL * 384 * 2 + 256;   // + OOB-read slack
    const size_t SZ_G   = 16UL * 384 * 384 * 2;    // 4.7 MB
    const size_t SZ_TP  = 16UL * 768 * 384 * 2;    // 9.4 MB
    const size_t SZ_W2  = 16UL * 384 * 384 * 2;    // 4.7 MB

    size_t off = 0;
    u16* xT    = (u16*)(ws + off); off += SZ_XT;
    u16* wqkvT = (u16*)(ws + off); off += SZ_WQT;
    u16* wv    = (u16*)(ws + off); off += SZ_WV;
    u16* woutT = (u16*)(ws + off); off += SZ_WOT;
    u16* Gs    = (u16*)(ws + off); off += SZ_G;
    u16* Tp    = (u16*)(ws + off); off += SZ_TP;
    u16* W2T   = (u16*)(ws + off); off += SZ_W2;
    u16* W3    = (u16*)(ws + off);

    // 1) x -> xT ; w_qkv -> wqkvT + wv ; w_out -> woutT
    transpose_all<<<dim3(36, 6, 18), 256, 0, stream>>>(
        x, w_qkv, w_out, xT, wqkvT, wv, woutT);
    // 2) G[b] = X X^T directly from f32 x (bf16 swz out)
    g_gemm<<<dim3(3, 3, 16), 256, 0, stream>>>(x, Gs);
    // 3) T'[b] = W_qk^T G (plain bf16 [768][384])
    mfma_gemm<0, 6, 6, 3><<<dim3(6, 3, 16), 256, 0, stream>>>(
        wqkvT, 0L, Gs, 384L * 384, Tp, 768L * 384, 384, nullptr);
    // 4) fused S + softmax + fold -> W2T (bf16 swz)
    sm_fold<<<dim3(8, 16), 256, 0, stream>>>(Tp, wqkvT, temp, woutT, W2T);
    // 5) W3[b] = W2^T Wv (bf16 swz)
    mfma_gemm<2, 6, 3, 3><<<dim3(3, 3, 16), 256, 0, stream>>>(
        W2T, 384L * 384, wv, 0L, W3, 384L * 384, 384, nullptr);
    // 6) out[b] = W3 X + b_out (f32)
    mfma_gemm<1, 6, 3, 18><<<dim3(3, 18, 16), 256, 0, stream>>>(
        W3, 384L * 384, xT, 384L * 2304, out, 384L * 2304, 2304, b_out);
}

// Round 9
// 124.024 us; speedup vs baseline: 1.2186x; 1.2186x over previous
//
#include <hip/hip_runtime.h>
#include <cstdint>

typedef __attribute__((ext_vector_type(8))) short short8;
typedef __attribute__((ext_vector_type(4))) float f32x4;
typedef unsigned int u32;
typedef unsigned short u16;

#define NTOK 2304
#define CDIM 384

__device__ __forceinline__ u16 f2bf(float f) {
    u32 u = __builtin_bit_cast(u32, f);
    u32 r = (u + 0x7FFFu + ((u >> 16) & 1u)) >> 16;
    return (u16)r;
}
__device__ __forceinline__ float bf2f(u32 h) {
    u32 u = h << 16;
    return __builtin_bit_cast(float, u);
}

// ---------------------------------------------------------------------------
// Merged transpose/cast.
// bz < 16 : x[bz] [384][2304] -> xT [2304][384] swz AND xbf [384][2304] swz
// bz == 16: w_qkv [384][1152] -> wqkvT [1152][384] swz; cols>=768 -> wv cast
// bz == 17: w_out [384][384]  -> woutT [384 j][384 cc] swz  (T only)
// swizzle: byte' = byte ^ ((row&7)<<4) on 16B chunks within each row.
// ---------------------------------------------------------------------------
__global__ __launch_bounds__(256) void transpose_all(
    const float* __restrict__ x, const float* __restrict__ w_qkv,
    const float* __restrict__ w_out,
    u16* __restrict__ xT, u16* __restrict__ xbf,
    u16* __restrict__ wqkvT, u16* __restrict__ wv, u16* __restrict__ woutT)
{
    __shared__ float tile[64][65];
    const int bz = blockIdx.z;
    const float* src; int Csz; char* dT; char* dC = nullptr;
    int dcCol0 = 0; long dcRowB = 0;
    if (bz < 16) {
        src = x + (long)bz * 384 * 2304; Csz = 2304;
        dT = (char*)(xT + (long)bz * 2304 * 384);
        dC = (char*)(xbf + (long)bz * 384 * 2304);
        dcCol0 = 0; dcRowB = 2304 * 2;
    } else if (bz == 16) {
        if (blockIdx.x >= 18) return;
        src = w_qkv; Csz = 1152;
        dT = (char*)wqkvT; dC = (char*)wv; dcCol0 = 768; dcRowB = 768;
    } else {
        if (blockIdx.x >= 6) return;
        src = w_out; Csz = 384;
        dT = (char*)woutT;
    }
    const int c0 = blockIdx.x * 64;   // col-tile of src
    const int k0 = blockIdx.y * 64;   // row-tile of src
    const int t = threadIdx.x;
    const int rr = t >> 2, cc4 = (t & 3) * 16;

    const float* srow = src + (long)(k0 + rr) * Csz + c0 + cc4;
#pragma unroll
    for (int i = 0; i < 4; ++i) {
        float4 v = *(const float4*)(srow + i * 4);
        tile[rr][cc4 + i*4 + 0] = v.x;
        tile[rr][cc4 + i*4 + 1] = v.y;
        tile[rr][cc4 + i*4 + 2] = v.z;
        tile[rr][cc4 + i*4 + 3] = v.w;
    }
    __syncthreads();

    // transposed output: rows = c0+rr (src cols), row length 384
    {
        char* drow = dT + (long)(c0 + rr) * (CDIM * 2);
        const int sw = (rr & 7) << 4;
#pragma unroll
        for (int half = 0; half < 2; ++half) {
            u32 pk[4];
#pragma unroll
            for (int i = 0; i < 4; ++i) {
                float v0 = tile[cc4 + half*8 + 2*i][rr];
                float v1 = tile[cc4 + half*8 + 2*i + 1][rr];
                pk[i] = (u32)f2bf(v0) | ((u32)f2bf(v1) << 16);
            }
            uint4 q; q.x = pk[0]; q.y = pk[1]; q.z = pk[2]; q.w = pk[3];
            const int inrow = (k0 + cc4 + half*8) * 2;
            *(uint4*)(drow + (inrow ^ sw)) = q;
        }
    }
    // cast output: rows = k0+rr (src rows), cols c0-dcCol0..
    if (dC && c0 >= dcCol0) {
        char* drow = dC + (long)(k0 + rr) * dcRowB;
        const int sw = (rr & 7) << 4;
#pragma unroll
        for (int half = 0; half < 2; ++half) {
            u32 pk[4];
#pragma unroll
            for (int i = 0; i < 4; ++i) {
                float v0 = tile[rr][cc4 + half*8 + 2*i];
                float v1 = tile[rr][cc4 + half*8 + 2*i + 1];
                pk[i] = (u32)f2bf(v0) | ((u32)f2bf(v1) << 16);
            }
            uint4 q; q.x = pk[0]; q.y = pk[1]; q.z = pk[2]; q.w = pk[3];
            const int inrow = (c0 - dcCol0 + cc4 + half*8) * 2;
            *(uint4*)(drow + (inrow ^ sw)) = q;
        }
    }
}

// ---------------------------------------------------------------------------
// Generalized MFMA GEMM (proven): O[b][m][n] = sum_k A[m][k]*B[n][k].
// A,B bf16 rows of KT*64 elems, XOR-swizzled. 128x128 tile, BK=64, 4 waves,
// dbuf global_load_lds. XCD-aware bijective block swizzle (NWG % 8 == 0).
// MODE 0: bf16 plain rows; MODE 1: f32 + bias; MODE 2: bf16 swz rows.
// ---------------------------------------------------------------------------
template<int MODE, int KT, int GX, int GY>
__global__ __launch_bounds__(256) void mfma_gemm(
    const u16* __restrict__ A, long aBatch,
    const u16* __restrict__ Bm, long bBatch,
    void* __restrict__ Ovoid, long oBatch, int ostride,
    const float* __restrict__ bias)
{
    constexpr int KB  = KT * 128;
    constexpr int KE  = KT * 64;
    constexpr int NWG = GX * GY * 16;
    __shared__ __attribute__((aligned(16))) u16 As[2][128 * 64];
    __shared__ __attribute__((aligned(16))) u16 Bs[2][128 * 64];

    const int lid = blockIdx.x + GX * (blockIdx.y + GY * blockIdx.z);
    const int swzid = (lid & 7) * (NWG / 8) + (lid >> 3);
    const int b   = swzid / (GX * GY);
    const int rem = swzid % (GX * GY);
    const int m0 = (rem % GX) * 128, n0 = (rem / GX) * 128;

    const u16* Ab = A + (long)b * aBatch + (long)m0 * KE;
    const u16* Bb = Bm + (long)b * bBatch + (long)n0 * KE;
    const int t = threadIdx.x;
    const int w = t >> 6, l = t & 63;
    const int wm = (w >> 1) * 64, wn = (w & 1) * 64;
    const int srow = t >> 3;
    const int scol = (t & 7) * 16;
    f32x4 acc[4][4] = {};

    auto stage = [&](int buf, int kt) {
        const int kbyte = kt * 128;
#pragma unroll
        for (int i = 0; i < 4; ++i) {
            const int row = srow + i * 32;
            const long so = (long)row * KB + kbyte + scol;
            const int d = (i * 256 + t) * 16;
            __builtin_amdgcn_global_load_lds(
                (const __attribute__((address_space(1))) u32*)((const char*)Ab + so),
                (__attribute__((address_space(3))) u32*)((char*)&As[buf][0] + d), 16, 0, 0);
            __builtin_amdgcn_global_load_lds(
                (const __attribute__((address_space(1))) u32*)((const char*)Bb + so),
                (__attribute__((address_space(3))) u32*)((char*)&Bs[buf][0] + d), 16, 0, 0);
        }
    };

    stage(0, 0);
    __syncthreads();
    int cur = 0;
#pragma unroll 1
    for (int kt = 0; kt < KT; ++kt) {
        if (kt < KT - 1) stage(cur ^ 1, kt + 1);
        const char* Ac = (const char*)&As[cur][0];
        const char* Bc = (const char*)&Bs[cur][0];
#pragma unroll
        for (int kk = 0; kk < 2; ++kk) {
            short8 af[4], bfr[4];
#pragma unroll
            for (int mi = 0; mi < 4; ++mi) {
                const int m = wm + mi * 16 + (l & 15);
                const int off = m * 128 + ((kk * 64 + (l >> 4) * 16) ^ ((m & 7) << 4));
                af[mi] = *(const short8*)(Ac + off);
            }
#pragma unroll
            for (int ni = 0; ni < 4; ++ni) {
                const int n = wn + ni * 16 + (l & 15);
                const int off = n * 128 + ((kk * 64 + (l >> 4) * 16) ^ ((n & 7) << 4));
                bfr[ni] = *(const short8*)(Bc + off);
            }
#pragma unroll
            for (int mi = 0; mi < 4; ++mi)
#pragma unroll
                for (int ni = 0; ni < 4; ++ni)
                    acc[mi][ni] = __builtin_amdgcn_mfma_f32_16x16x32_bf16(
                        af[mi], bfr[ni], acc[mi][ni], 0, 0, 0);
        }
        __syncthreads();
        cur ^= 1;
    }

    if (MODE == 0) {
        u16* O = (u16*)Ovoid + (long)b * oBatch;
#pragma unroll
        for (int mi = 0; mi < 4; ++mi) {
            const int mb = m0 + wm + mi * 16 + (l >> 4) * 4;
#pragma unroll
            for (int ni = 0; ni < 4; ++ni) {
                const int n = n0 + wn + ni * 16 + (l & 15);
#pragma unroll
                for (int r = 0; r < 4; ++r)
                    O[(long)(mb + r) * ostride + n] = f2bf(acc[mi][ni][r]);
            }
        }
    } else if (MODE == 1) {
        float* O = (float*)Ovoid + (long)b * oBatch;
#pragma unroll
        for (int mi = 0; mi < 4; ++mi) {
            const int mb = m0 + wm + mi * 16 + (l >> 4) * 4;
#pragma unroll
            for (int r = 0; r < 4; ++r) {
                const float bb = bias[mb + r];
#pragma unroll
                for (int ni = 0; ni < 4; ++ni) {
                    const int n = n0 + wn + ni * 16 + (l & 15);
                    O[(long)(mb + r) * ostride + n] = acc[mi][ni][r] + bb;
                }
            }
        }
    } else {
        char* Ob = (char*)Ovoid + (long)b * oBatch * 2;
#pragma unroll
        for (int mi = 0; mi < 4; ++mi) {
            const int mb = m0 + wm + mi * 16 + (l >> 4) * 4;
#pragma unroll
            for (int ni = 0; ni < 4; ++ni) {
                const int n = n0 + wn + ni * 16 + (l & 15);
#pragma unroll
                for (int r = 0; r < 4; ++r) {
                    const int m = mb + r;
                    const long byteoff = (long)m * (ostride * 2) +
                        (((long)n * 2) ^ ((m & 7) << 4));
                    *(u16*)(Ob + byteoff) = f2bf(acc[mi][ni][r]);
                }
            }
        }
    }
}

// ---------------------------------------------------------------------------
// Fused: S (MFMA) -> diag norms -> softmax -> S bf16 in LDS -> MFMA fold
// with woutT -> W2T bf16 swz. One block per (b,h). (round-8 proven)
// ---------------------------------------------------------------------------
__global__ __launch_bounds__(256) void sm_fold(
    const u16* __restrict__ Tp,     // [16][768][384] plain bf16
    const u16* __restrict__ wT,     // [1152][384] swz bf16
    const float* __restrict__ temp,
    const u16* __restrict__ woutT,  // [384 j][384 cc] swz bf16 (+slack)
    u16* __restrict__ W2T)          // [16][384][384] swz bf16
{
    __shared__ float Sp[4][48][48];
    __shared__ float S[48][49];
    __shared__ float invk[48], invq[48];
    __shared__ __attribute__((aligned(16))) u16 Sbf[48 * 64];
    const int h = blockIdx.x, b = blockIdx.y, t = threadIdx.x;
    const int w = t >> 6, l = t & 63, lr = l & 15, lk = (l >> 4) * 8;
    const int h48 = h * 48;

    // ---- S partials ----
    const u16* Tk = Tp + ((long)b * 768 + 384 + h48) * CDIM;
    {
        f32x4 acc[3][3] = {};
#pragma unroll
        for (int ks = 0; ks < 3; ++ks) {
            const int k0 = w * 96 + ks * 32 + lk;
            short8 af[3], bfr[3];
#pragma unroll
            for (int mi = 0; mi < 3; ++mi)
                af[mi] = *(const short8*)(Tk + (long)(mi * 16 + lr) * CDIM + k0);
#pragma unroll
            for (int ni = 0; ni < 3; ++ni) {
                const int row = h48 + ni * 16 + lr;
                const char* base = (const char*)wT + (long)row * 768;
                bfr[ni] = *(const short8*)(base + ((k0 * 2) ^ ((row & 7) << 4)));
            }
#pragma unroll
            for (int mi = 0; mi < 3; ++mi)
#pragma unroll
                for (int ni = 0; ni < 3; ++ni)
                    acc[mi][ni] = __builtin_amdgcn_mfma_f32_16x16x32_bf16(
                        af[mi], bfr[ni], acc[mi][ni], 0, 0, 0);
        }
#pragma unroll
        for (int mi = 0; mi < 3; ++mi)
#pragma unroll
            for (int ni = 0; ni < 3; ++ni)
#pragma unroll
                for (int r = 0; r < 4; ++r)
                    Sp[w][mi * 16 + (l >> 4) * 4 + r][ni * 16 + lr] = acc[mi][ni][r];
    }
    // ---- diag norms ----
    if (t < 96) {
        const int ch = (t < 48) ? (h48 + t) : (384 + h48 + (t - 48));
        const u16* trow = Tp + ((long)b * 768 + ch) * CDIM;
        const char* wrow = (const char*)wT + (long)ch * 768;
        const int sw = (ch & 7) << 4;
        float s = 0.f;
#pragma unroll 4
        for (int i = 0; i < 48; ++i) {
            short8 tv = *(const short8*)(trow + i * 8);
            short8 wv = *(const short8*)(wrow + ((i * 16) ^ sw));
#pragma unroll
            for (int e = 0; e < 8; ++e)
                s += bf2f((u16)tv[e]) * bf2f((u16)wv[e]);
        }
        float inv = 1.0f / fmaxf(sqrtf(fmaxf(s, 0.f)), 1e-12f);
        if (t < 48) invq[t] = inv; else invk[t - 48] = inv;
    }
    __syncthreads();
    for (int idx = t; idx < 2304; idx += 256) {
        const int p = idx / 48, q = idx % 48;
        S[p][q] = Sp[0][p][q] + Sp[1][p][q] + Sp[2][p][q] + Sp[3][p][q];
    }
    __syncthreads();
    // ---- softmax -> Sbf (bf16, 64-col zero-padded, swz) ----
    if (t < 48) {
        const float sc = temp[h] * invk[t];
        float row[48];
        float mx = -1e30f;
#pragma unroll 8
        for (int q = 0; q < 48; ++q) {
            row[q] = S[t][q] * sc * invq[q];
            mx = fmaxf(mx, row[q]);
        }
        float ssum = 0.f;
#pragma unroll 8
        for (int q = 0; q < 48; ++q) {
            row[q] = __expf(row[q] - mx);
            ssum += row[q];
        }
        float inv = 1.0f / ssum;
        const int sw = (t & 7) << 4;
#pragma unroll
        for (int g = 0; g < 8; ++g) {
            u32 pk[4];
#pragma unroll
            for (int e = 0; e < 4; ++e) {
                const int q0 = g * 8 + 2 * e;
                float v0 = (q0 < 48) ? row[q0] * inv : 0.f;
                float v1 = (q0 + 1 < 48) ? row[q0 + 1] * inv : 0.f;
                pk[e] = (u32)f2bf(v0) | ((u32)f2bf(v1) << 16);
            }
            uint4 qv; qv.x = pk[0]; qv.y = pk[1]; qv.z = pk[2]; qv.w = pk[3];
            *(uint4*)((char*)Sbf + t * 128 + ((g * 16) ^ sw)) = qv;
        }
    }
    __syncthreads();
    // ---- fold via MFMA: W2[p][j] = sum_q S[p][q] w_out[h48+q][j] ----
    {
        const char* SbfB = (const char*)Sbf;
        const int jw = w * 96;
        f32x4 fac[3][6] = {};
#pragma unroll
        for (int ks = 0; ks < 2; ++ks) {
            const int ka = ks * 64 + (l >> 4) * 16;   // byte k-offset (A)
            const int kb = h * 96 + ka;               // byte k-offset (B)
            short8 af[3], bfr[6];
#pragma unroll
            for (int mi = 0; mi < 3; ++mi) {
                const int p = mi * 16 + lr;
                af[mi] = *(const short8*)(SbfB + p * 128 + (ka ^ ((p & 7) << 4)));
            }
#pragma unroll
            for (int ni = 0; ni < 6; ++ni) {
                const int j = jw + ni * 16 + lr;
                bfr[ni] = *(const short8*)((const char*)woutT + (long)j * 768 +
                                           (kb ^ ((j & 7) << 4)));
            }
#pragma unroll
            for (int mi = 0; mi < 3; ++mi)
#pragma unroll
                for (int ni = 0; ni < 6; ++ni)
                    fac[mi][ni] = __builtin_amdgcn_mfma_f32_16x16x32_bf16(
                        af[mi], bfr[ni], fac[mi][ni], 0, 0, 0);
        }
        char* Wb = (char*)W2T + (long)b * 294912;
#pragma unroll
        for (int mi = 0; mi < 3; ++mi)
#pragma unroll
            for (int ni = 0; ni < 6; ++ni)
#pragma unroll
                for (int r = 0; r < 4; ++r) {
                    const int p = mi * 16 + (l >> 4) * 4 + r;
                    const int j = jw + ni * 16 + lr;
                    const long byteoff = (long)j * 768 +
                        (((h48 + p) * 2) ^ ((j & 7) << 4));
                    *(u16*)(Wb + byteoff) = f2bf(fac[mi][ni][r]);
                }
    }
}

// ---------------------------------------------------------------------------
extern "C" void kernel_launch(void* const* d_in, const int* in_sizes, int n_in,
                              void* d_out, int out_size, void* d_ws, size_t ws_size,
                              hipStream_t stream) {
    const float* x     = (const float*)d_in[0];  // [16][384][2304]
    const float* w_qkv = (const float*)d_in[1];  // [384][1152]
    const float* temp  = (const float*)d_in[2];  // [8]
    const float* w_out = (const float*)d_in[3];  // [384][384]
    const float* b_out = (const float*)d_in[4];  // [384]
    float* out = (float*)d_out;                  // [16][384][2304]

    char* ws = (char*)d_ws;
    const size_t SZ_XBF = 16UL * 384 * 2304 * 2;   // 28.3 MB
    const size_t SZ_XT  = 16UL * 2304 * 384 * 2;   // 28.3 MB
    const size_t SZ_WQT = 1152UL * 384 * 2;        // 0.88 MB
    const size_t SZ_WV  = 384UL * 384 * 2;         // 0.29 MB
    const size_t SZ_WOT = 384UL * 384 * 2 + 256;   // + OOB-read slack
    const size_t SZ_G   = 16UL * 384 * 384 * 2;    // 4.7 MB
    const size_t SZ_TP  = 16UL * 768 * 384 * 2;    // 9.4 MB
    const size_t SZ_W2  = 16UL * 384 * 384 * 2;    // 4.7 MB

    size_t off = 0;
    u16* xbf   = (u16*)(ws + off); off += SZ_XBF;
    u16* xT    = (u16*)(ws + off); off += SZ_XT;
    u16* wqkvT = (u16*)(ws + off); off += SZ_WQT;
    u16* wv    = (u16*)(ws + off); off += SZ_WV;
    u16* woutT = (u16*)(ws + off); off += SZ_WOT;
    u16* Gs    = (u16*)(ws + off); off += SZ_G;
    u16* Tp    = (u16*)(ws + off); off += SZ_TP;
    u16* W2T   = (u16*)(ws + off); off += SZ_W2;
    u16* W3    = (u16*)(ws + off);

    // 1) x -> xT + xbf ; w_qkv -> wqkvT + wv ; w_out -> woutT
    transpose_all<<<dim3(36, 6, 18), 256, 0, stream>>>(
        x, w_qkv, w_out, xT, xbf, wqkvT, wv, woutT);
    // 2) G[b] = X X^T (bf16 swz out, gload_lds path)
    mfma_gemm<2, 36, 3, 3><<<dim3(3, 3, 16), 256, 0, stream>>>(
        xbf, 384L * 2304, xbf, 384L * 2304, Gs, 384L * 384, 384, nullptr);
    // 3) T'[b] = W_qk^T G (plain bf16 [768][384])
    mfma_gemm<0, 6, 6, 3><<<dim3(6, 3, 16), 256, 0, stream>>>(
        wqkvT, 0L, Gs, 384L * 384, Tp, 768L * 384, 384, nullptr);
    // 4) fused S + softmax + fold -> W2T (bf16 swz)
    sm_fold<<<dim3(8, 16), 256, 0, stream>>>(Tp, wqkvT, temp, woutT, W2T);
    // 5) W3[b] = W2^T Wv (bf16 swz)
    mfma_gemm<2, 6, 3, 3><<<dim3(3, 3, 16), 256, 0, stream>>>(
        W2T, 384L * 384, wv, 0L, W3, 384L * 384, 384, nullptr);
    // 6) out[b] = W3 X + b_out (f32)
    mfma_gemm<1, 6, 3, 18><<<dim3(3, 18, 16), 256, 0, stream>>>(
        W3, 384L * 384, xT, 384L * 2304, out, 384L * 2304, 2304, b_out);
}